// Round 15
// baseline (786.055 us; speedup 1.0000x reference)
//
#include <hip/hip_runtime.h>
#include <hip/hip_bf16.h>
#include <stdint.h>

// Problem constants
#define KK 4
#define BB 16
#define LL 4096
#define DD 512
#define HH 128

typedef __attribute__((ext_vector_type(8))) short bf16x8;
typedef __attribute__((ext_vector_type(4))) float f32x4;
typedef __attribute__((ext_vector_type(4))) unsigned int u32x4;

__device__ __forceinline__ unsigned int pack_bf16(float lo, float hi) {
  unsigned int a = __float_as_uint(lo);
  unsigned int b = __float_as_uint(hi);
  a = (a + 0x7FFFu + ((a >> 16) & 1u)) >> 16;   // RNE f32->bf16
  b = (b + 0x7FFFu + ((b >> 16) & 1u)) >> 16;
  return a | (b << 16);
}

__device__ __forceinline__ bf16x8 packfrag(f32x4 v0, f32x4 v1) {
  u32x4 p;
  p.x = pack_bf16(v0.x, v0.y);
  p.y = pack_bf16(v0.z, v0.w);
  p.z = pack_bf16(v1.x, v1.y);
  p.w = pack_bf16(v1.z, v1.w);
  return __builtin_bit_cast(bf16x8, p);
}

// x + quad_perm<CTRL>(x): VALU-pipe cross-lane add within each 4-lane quad.
template <int CTRL>
__device__ __forceinline__ float qadd(float x) {
  int y = __builtin_amdgcn_update_dpp(0, __float_as_int(x), CTRL, 0xF, 0xF, true);
  return x + __int_as_float(y);
}

__device__ __forceinline__ void load_lds16(const void* g, void* l) {
  // DMA 16B/lane: LDS dest = wave-uniform base + lane*16.
  __builtin_amdgcn_global_load_lds(
      (const __attribute__((address_space(1))) unsigned int*)g,
      (__attribute__((address_space(3))) unsigned int*)l, 16, 0, 0);
}

// ---------------- prep kernel: wf (blocks 0-31) + q_bias (block 32) ----------
// wf chunk gid = (ks*8 + nt)*64 + lane holds 8 bf16 (MFMA B-fragment):
//   element j: W[nt*16 + (lane&15)][ks*32 + (lane>>4)*8 + j]   (natural d)
__global__ void prep_kernel(const float* __restrict__ ln_w,
                            const float* __restrict__ ln_b,
                            const float* __restrict__ vq,
                            unsigned int* __restrict__ wf,
                            float* __restrict__ qb) {
  if (blockIdx.x == 32) {
    int h = threadIdx.x;
    if (h < HH) {
      float acc = ln_b[h];
      const float* wq = ln_w + (size_t)h * (DD + HH) + DD;
      for (int j = 0; j < HH; ++j) acc = fmaf(wq[j], vq[j], acc);
      qb[h] = acc;
    }
    return;
  }
  int gid = blockIdx.x * 256 + threadIdx.x;   // 0..8191
  int ks = gid >> 9;
  int nt = (gid >> 6) & 7;
  int lane = gid & 63;
  int h = nt * 16 + (lane & 15);
  int d0 = ks * 32 + (lane >> 4) * 8;
  const float* src = ln_w + (size_t)h * (DD + HH) + d0;
  u32x4 v;
  v.x = pack_bf16(src[0], src[1]);
  v.y = pack_bf16(src[2], src[3]);
  v.z = pack_bf16(src[4], src[5]);
  v.w = pack_bf16(src[6], src[7]);
  *(u32x4*)(wf + (size_t)gid * 4) = v;
}

// ---------------- main fused kernel: ZERO barriers after prologue ----------
// 256 blocks x 512 threads (1 block/CU, 8 waves). W_h staged once into LDS
// (128 KB, one __syncthreads), then waves run fully independently — no
// per-tile barriers, no burst staging: next-group A loads (2 x f32x4) are
// interleaved into every K-step, so the CU's HBM read queue never empties
// (the R4-R14 150µs plateau = per-tile burst + barrier queue-drain, common
// to every variant tried).
// Wave owns 32 positions = 8 groups of 16 MFMA rows m = pos*4 + k.
// Lane l: A-row m = l&15 (k = m&3 plane, pos-offset m>>2), d-cols (l>>4)*8.
// Per K-step: 8 W ds_read_b128 (lane-linear, conflict-free) + 8 MFMA.
// C/D: pos = lane>>4, k = reg j -> softmax over k fully in-lane after a
// 16-lane shfl_xor h-reduce; k-weighted sum = DPP quad butterfly (k = lane
// bits 0-1); stores from kk==0 lanes (128B-contiguous d-chunks per row).
__global__ __launch_bounds__(512) void agg_main(
    const float* __restrict__ hs, const unsigned int* __restrict__ wf,
    const float* __restrict__ qb, const float* __restrict__ vw,
    float* __restrict__ out) {
  extern __shared__ char smem[];
  char* smemW = smem;                        // 131072 B: W fragments, linear
  float* qb_l = (float*)(smem + 131072);     // 512 B
  float* vw_l = (float*)(smem + 131584);     // 512 B

  const int tid = threadIdx.x;
  const int lane = tid & 63;
  const int wv = tid >> 6;            // 0..7
  const int m = lane & 15;            // A-row index
  const int kk = m & 3;               // hs k-plane this lane loads
  const int pp = m >> 2;              // pos offset within group
  const int cg = lane >> 4;           // d col-group / C-D pos group

  // ---- prologue: stage W via DMA + qb/vw to LDS; ONE barrier ----
#pragma unroll
  for (int i = 0; i < 16; ++i)
    load_lds16(wf + (size_t)(i * 512 + tid) * 4, smemW + (i * 512 + tid) * 16);
  if (tid < HH) {
    qb_l[tid] = qb[tid];
    vw_l[tid] = vw[tid];
  }
  __syncthreads();                    // W resident; waves independent from here

  const int b = blockIdx.x >> 4;
  const int lw = ((blockIdx.x & 15) << 8) + wv * 32;  // wave's 32 positions

  auto aptr = [&](int l0) -> const float* {
    return hs + (((size_t)(kk * BB + b)) * LL + (l0 + pp)) * DD + cg * 8;
  };

  bf16x8 aC[16], aN[16];

  // ---- load + pack group 0 ----
  {
    const float* ap = aptr(lw);
#pragma unroll
    for (int ks = 0; ks < 16; ++ks) {
      f32x4 v0 = *(const f32x4*)(ap + ks * 32);
      f32x4 v1 = *(const f32x4*)(ap + ks * 32 + 4);
      aC[ks] = packfrag(v0, v1);
    }
  }

  // One group: GEMM on `cur` with next-group loads interleaved into `nxt`,
  // then wave-local softmax + weighted sum + stores. No synchronization.
  auto body = [&](int l0, bf16x8 (&cur)[16], bf16x8 (&nxt)[16], bool more) {
    const float* np = aptr(l0 + 4);
    f32x4 sl[4][2];                   // rotating raw window (static idx: unrolled)
    f32x4 acc[8];
#pragma unroll
    for (int nt = 0; nt < 8; ++nt) acc[nt] = (f32x4){0.f, 0.f, 0.f, 0.f};

#pragma unroll
    for (int ks = 0; ks < 16; ++ks) {
      if (more) {
        if (ks >= 4) nxt[ks - 4] = packfrag(sl[ks & 3][0], sl[ks & 3][1]);
        sl[ks & 3][0] = *(const f32x4*)(np + ks * 32);
        sl[ks & 3][1] = *(const f32x4*)(np + ks * 32 + 4);
      }
#pragma unroll
      for (int nt = 0; nt < 8; ++nt) {
        bf16x8 w = *(const bf16x8*)(smemW + ((ks * 8 + nt) * 64 + lane) * 16);
        acc[nt] =
            __builtin_amdgcn_mfma_f32_16x16x32_bf16(cur[ks], w, acc[nt], 0, 0, 0);
      }
    }
    if (more) {
#pragma unroll
      for (int ks = 12; ks < 16; ++ks)
        nxt[ks] = packfrag(sl[ks & 3][0], sl[ks & 3][1]);
    }

    // ---- scores: s[k=j, pos=cg] = sum_h vw[h]*tanh(z + qb[h]) ----
    float qbv[8], vwv[8];
#pragma unroll
    for (int nt = 0; nt < 8; ++nt) {
      qbv[nt] = qb_l[nt * 16 + m];    // broadcast within 16-lane groups
      vwv[nt] = vw_l[nt * 16 + m];
    }
    float ps[4];
#pragma unroll
    for (int j = 0; j < 4; ++j) {
      float s = 0.f;
#pragma unroll
      for (int nt = 0; nt < 8; ++nt) {
        float z = acc[nt][j] + qbv[nt];
        z = fminf(15.f, fmaxf(-15.f, z));
        float e = __expf(-2.f * z);
        float th = (1.f - e) * __builtin_amdgcn_rcpf(1.f + e);
        s = fmaf(vwv[nt], th, s);
      }
#pragma unroll
      for (int msk = 1; msk < 16; msk <<= 1) s += __shfl_xor(s, msk, 64);
      ps[j] = s;
    }
    // softmax over k (= j) for pos = cg; mask dropped: uniform per-(b,l)
    // shift is softmax-invariant
    float mx = fmaxf(fmaxf(ps[0], ps[1]), fmaxf(ps[2], ps[3]));
    float e0 = __expf(ps[0] - mx), e1 = __expf(ps[1] - mx);
    float e2 = __expf(ps[2] - mx), e3 = __expf(ps[3] - mx);
    float inv = __builtin_amdgcn_rcpf(e0 + e1 + e2 + e3);
    float a0 = e0 * inv, a1 = e1 * inv, a2 = e2 * inv, a3 = e3 * inv;
    // redistribute: this lane's A-rows are (k=kk, pos=pp); a for pos=pp
    // lives (uniformly) in lane group pp
    int srcl = (pp << 4) | m;
    float t0 = __shfl(a0, srcl, 64);
    float t1 = __shfl(a1, srcl, 64);
    float t2 = __shfl(a2, srcl, 64);
    float t3 = __shfl(a3, srcl, 64);
    float av = kk == 0 ? t0 : (kk == 1 ? t1 : (kk == 2 ? t2 : t3));

    // ---- weighted sum over k: quad butterfly (k = lane bits 0-1) ----
    float* ob = out + (((size_t)b) * LL + (l0 + pp)) * DD + cg * 8;
#pragma unroll
    for (int ks = 0; ks < 16; ++ks) {
      u32x4 u = __builtin_bit_cast(u32x4, cur[ks]);
      float x0 = av * __uint_as_float(u.x << 16);
      float x1 = av * __uint_as_float(u.x & 0xffff0000u);
      float x2 = av * __uint_as_float(u.y << 16);
      float x3 = av * __uint_as_float(u.y & 0xffff0000u);
      float x4 = av * __uint_as_float(u.z << 16);
      float x5 = av * __uint_as_float(u.z & 0xffff0000u);
      float x6 = av * __uint_as_float(u.w << 16);
      float x7 = av * __uint_as_float(u.w & 0xffff0000u);
      x0 = qadd<0xB1>(x0); x1 = qadd<0xB1>(x1);
      x2 = qadd<0xB1>(x2); x3 = qadd<0xB1>(x3);
      x4 = qadd<0xB1>(x4); x5 = qadd<0xB1>(x5);
      x6 = qadd<0xB1>(x6); x7 = qadd<0xB1>(x7);
      x0 = qadd<0x4E>(x0); x1 = qadd<0x4E>(x1);
      x2 = qadd<0x4E>(x2); x3 = qadd<0x4E>(x3);
      x4 = qadd<0x4E>(x4); x5 = qadd<0x4E>(x5);
      x6 = qadd<0x4E>(x6); x7 = qadd<0x4E>(x7);
      if (kk == 0) {
        f32x4 o0 = {x0, x1, x2, x3};
        f32x4 o1 = {x4, x5, x6, x7};
        __builtin_nontemporal_store(o0, (f32x4*)(ob + ks * 32));
        __builtin_nontemporal_store(o1, (f32x4*)(ob + ks * 32 + 4));
      }
    }
  };

  for (int gg = 0; gg < 4; ++gg) {    // 8 groups, aC/aN ping-pong
    body(lw + gg * 8, aC, aN, true);
    body(lw + gg * 8 + 4, aN, aC, gg < 3);
  }
}

extern "C" void kernel_launch(void* const* d_in, const int* in_sizes, int n_in,
                              void* d_out, int out_size, void* d_ws, size_t ws_size,
                              hipStream_t stream) {
  const float* hs   = (const float*)d_in[0];
  // d_in[1] = mask (int32) — unused: softmax over k is invariant to the
  // per-(b,l) uniform -1e4 shift, so the mask cannot affect x.
  const float* ln_w = (const float*)d_in[2];
  const float* ln_b = (const float*)d_in[3];
  const float* v_w  = (const float*)d_in[4];
  const float* vq   = (const float*)d_in[5];
  float* out = (float*)d_out;

  unsigned int* wf = (unsigned int*)d_ws;          // 128KB fragment-ordered bf16 W_h
  float* qb = (float*)((char*)d_ws + 131072);      // 512B q_bias

  prep_kernel<<<33, 256, 0, stream>>>(ln_w, ln_b, vq, wf, qb);
  agg_main<<<256, 512, 132096, stream>>>(hs, wf, qb, v_w, out);
}

// Round 16
// 653.674 us; speedup vs baseline: 1.2025x; 1.2025x over previous
//
#include <hip/hip_runtime.h>
#include <hip/hip_bf16.h>
#include <stdint.h>

// Problem constants
#define KK 4
#define BB 16
#define LL 4096
#define DD 512
#define HH 128

typedef __attribute__((ext_vector_type(8))) short bf16x8;
typedef __attribute__((ext_vector_type(4))) float f32x4;
typedef __attribute__((ext_vector_type(4))) unsigned int u32x4;

__device__ __forceinline__ unsigned int pack_bf16(float lo, float hi) {
  unsigned int a = __float_as_uint(lo);
  unsigned int b = __float_as_uint(hi);
  a = (a + 0x7FFFu + ((a >> 16) & 1u)) >> 16;   // RNE f32->bf16
  b = (b + 0x7FFFu + ((b >> 16) & 1u)) >> 16;
  return a | (b << 16);
}

__device__ __forceinline__ bf16x8 packfrag(f32x4 v0, f32x4 v1) {
  u32x4 p;
  p.x = pack_bf16(v0.x, v0.y);
  p.y = pack_bf16(v0.z, v0.w);
  p.z = pack_bf16(v1.x, v1.y);
  p.w = pack_bf16(v1.z, v1.w);
  return __builtin_bit_cast(bf16x8, p);
}

// x + quad_perm<CTRL>(x): VALU-pipe cross-lane add within each 4-lane quad.
template <int CTRL>
__device__ __forceinline__ float qadd(float x) {
  int y = __builtin_amdgcn_update_dpp(0, __float_as_int(x), CTRL, 0xF, 0xF, true);
  return x + __int_as_float(y);
}

__device__ __forceinline__ void load_lds16(const void* g, void* l) {
  // DMA 16B/lane: LDS dest = wave-uniform base + lane*16.
  __builtin_amdgcn_global_load_lds(
      (const __attribute__((address_space(1))) unsigned int*)g,
      (__attribute__((address_space(3))) unsigned int*)l, 16, 0, 0);
}

// ---------------- prep kernel: wf (blocks 0-31) + q_bias (block 32) ----------
// wf chunk gid = (ks*8 + nt)*64 + lane holds 8 bf16 (MFMA B-fragment):
//   element j: W[nt*16 + (lane&15)][ks*32 + (lane>>4)*8 + j]   (natural d)
__global__ void prep_kernel(const float* __restrict__ ln_w,
                            const float* __restrict__ ln_b,
                            const float* __restrict__ vq,
                            unsigned int* __restrict__ wf,
                            float* __restrict__ qb) {
  if (blockIdx.x == 32) {
    int h = threadIdx.x;
    if (h < HH) {
      float acc = ln_b[h];
      const float* wq = ln_w + (size_t)h * (DD + HH) + DD;
      for (int j = 0; j < HH; ++j) acc = fmaf(wq[j], vq[j], acc);
      qb[h] = acc;
    }
    return;
  }
  int gid = blockIdx.x * 256 + threadIdx.x;   // 0..8191
  int ks = gid >> 9;
  int nt = (gid >> 6) & 7;
  int lane = gid & 63;
  int h = nt * 16 + (lane & 15);
  int d0 = ks * 32 + (lane >> 4) * 8;
  const float* src = ln_w + (size_t)h * (DD + HH) + d0;
  u32x4 v;
  v.x = pack_bf16(src[0], src[1]);
  v.y = pack_bf16(src[2], src[3]);
  v.z = pack_bf16(src[4], src[5]);
  v.w = pack_bf16(src[6], src[7]);
  *(u32x4*)(wf + (size_t)gid * 4) = v;
}

// ---------------- main fused kernel: ZERO barriers after prologue ----------
// 256 blocks x 512 threads (1 block/CU, 8 waves). W_h staged once into LDS
// (128 KB, one __syncthreads), then waves run fully independently: per
// K-step the next fragment's 2 f32x4 loads are in a rolling 4-slot window
// (static indices), so every wave keeps ~8KB of HBM reads outstanding at
// all times and NO barrier ever drains the queue (the R4-R14 plateau's
// common mechanism). The epilogue RE-READS hs from L2/L3 (tile is
// cache-hot; ~60MB streams chip-wide between read and re-read << 256MB L3)
// so no A-fragment register arrays are needed: ~115 VGPR, no spill.
// Wave owns 32 positions = 8 groups of 16 MFMA rows m = pos*4 + k.
// Lane l: A-row m = l&15 (k-plane kk = m&3, pos-offset pp = m>>2), d-cols
// (l>>4)*8. C/D: pos = lane>>4, k = reg j -> softmax fully in-lane after a
// 16-lane shfl_xor h-reduce; k-weighted sum = DPP quad butterfly (k = lane
// bits 0-1); stores from kk==0 lanes (128B-contiguous per row per ks).
__global__ __launch_bounds__(512, 1) void agg_main(
    const float* __restrict__ hs, const unsigned int* __restrict__ wf,
    const float* __restrict__ qb, const float* __restrict__ vw,
    float* __restrict__ out) {
  extern __shared__ char smem[];
  char* smemW = smem;                        // 131072 B: W fragments, linear
  float* qb_l = (float*)(smem + 131072);     // 512 B
  float* vw_l = (float*)(smem + 131584);     // 512 B

  const int tid = threadIdx.x;
  const int lane = tid & 63;
  const int wv = tid >> 6;            // 0..7
  const int m = lane & 15;            // A-row index
  const int kk = m & 3;               // hs k-plane this lane loads
  const int pp = m >> 2;              // pos offset within group
  const int cg = lane >> 4;           // d col-group / C-D pos group

  // ---- prologue: stage W via DMA + qb/vw to LDS; ONE barrier ----
#pragma unroll
  for (int i = 0; i < 16; ++i)
    load_lds16(wf + (size_t)(i * 512 + tid) * 4, smemW + (i * 512 + tid) * 16);
  if (tid < HH) {
    qb_l[tid] = qb[tid];
    vw_l[tid] = vw[tid];
  }
  __syncthreads();                    // W resident; waves independent from here

  float qbv[8], vwv[8];
#pragma unroll
  for (int nt = 0; nt < 8; ++nt) {
    qbv[nt] = qb_l[nt * 16 + m];
    vwv[nt] = vw_l[nt * 16 + m];
  }

  const int b = blockIdx.x >> 4;
  const int lw = ((blockIdx.x & 15) << 8) + wv * 32;  // wave's 32 positions

  for (int g = 0; g < 8; ++g) {
    const int l0 = lw + g * 4;
    const float* ap =
        hs + (((size_t)(kk * BB + b)) * LL + (l0 + pp)) * DD + cg * 8;

    // ---- GEMM: rolling 4-slot prefetch (static slots), 8 MFMA per ks ----
    f32x4 acc[8];
#pragma unroll
    for (int nt = 0; nt < 8; ++nt) acc[nt] = (f32x4){0.f, 0.f, 0.f, 0.f};

    f32x4 sA0, sA1, sB0, sB1, sC0, sC1, sD0, sD1;
    sA0 = *(const f32x4*)(ap + 0);
    sA1 = *(const f32x4*)(ap + 4);
    sB0 = *(const f32x4*)(ap + 32);
    sB1 = *(const f32x4*)(ap + 36);
    sC0 = *(const f32x4*)(ap + 64);
    sC1 = *(const f32x4*)(ap + 68);
    sD0 = *(const f32x4*)(ap + 96);
    sD1 = *(const f32x4*)(ap + 100);

#pragma unroll
    for (int ks = 0; ks < 16; ++ks) {
      bf16x8 af;
      switch (ks & 3) {
        case 0:
          af = packfrag(sA0, sA1);
          if (ks + 4 < 16) {
            sA0 = *(const f32x4*)(ap + (ks + 4) * 32);
            sA1 = *(const f32x4*)(ap + (ks + 4) * 32 + 4);
          }
          break;
        case 1:
          af = packfrag(sB0, sB1);
          if (ks + 4 < 16) {
            sB0 = *(const f32x4*)(ap + (ks + 4) * 32);
            sB1 = *(const f32x4*)(ap + (ks + 4) * 32 + 4);
          }
          break;
        case 2:
          af = packfrag(sC0, sC1);
          if (ks + 4 < 16) {
            sC0 = *(const f32x4*)(ap + (ks + 4) * 32);
            sC1 = *(const f32x4*)(ap + (ks + 4) * 32 + 4);
          }
          break;
        default:
          af = packfrag(sD0, sD1);
          if (ks + 4 < 16) {
            sD0 = *(const f32x4*)(ap + (ks + 4) * 32);
            sD1 = *(const f32x4*)(ap + (ks + 4) * 32 + 4);
          }
          break;
      }
#pragma unroll
      for (int nt = 0; nt < 8; ++nt) {
        bf16x8 w = *(const bf16x8*)(smemW + ((ks * 8 + nt) * 64 + lane) * 16);
        acc[nt] =
            __builtin_amdgcn_mfma_f32_16x16x32_bf16(af, w, acc[nt], 0, 0, 0);
      }
    }

    // ---- scores: s[k=j, pos=cg] = sum_h vw[h]*tanh(z + qb[h]) ----
    float ps[4];
#pragma unroll
    for (int j = 0; j < 4; ++j) {
      float s = 0.f;
#pragma unroll
      for (int nt = 0; nt < 8; ++nt) {
        float z = acc[nt][j] + qbv[nt];
        z = fminf(15.f, fmaxf(-15.f, z));
        float e = __expf(-2.f * z);
        float th = (1.f - e) * __builtin_amdgcn_rcpf(1.f + e);
        s = fmaf(vwv[nt], th, s);
      }
#pragma unroll
      for (int msk = 1; msk < 16; msk <<= 1) s += __shfl_xor(s, msk, 64);
      ps[j] = s;
    }
    // softmax over k (= j) for pos = cg; mask dropped: uniform per-(b,l)
    // shift is softmax-invariant
    float mx = fmaxf(fmaxf(ps[0], ps[1]), fmaxf(ps[2], ps[3]));
    float e0 = __expf(ps[0] - mx), e1 = __expf(ps[1] - mx);
    float e2 = __expf(ps[2] - mx), e3 = __expf(ps[3] - mx);
    float inv = __builtin_amdgcn_rcpf(e0 + e1 + e2 + e3);
    float a0 = e0 * inv, a1 = e1 * inv, a2 = e2 * inv, a3 = e3 * inv;
    // redistribute: this lane's rows are (k=kk, pos=pp); pos=pp lives in
    // lane group pp (uniform across its 16 lanes after the shfl reduce)
    int srcl = (pp << 4) | m;
    float t0 = __shfl(a0, srcl, 64);
    float t1 = __shfl(a1, srcl, 64);
    float t2 = __shfl(a2, srcl, 64);
    float t3 = __shfl(a3, srcl, 64);
    float av = kk == 0 ? t0 : (kk == 1 ? t1 : (kk == 2 ? t2 : t3));

    // ---- weighted sum: RE-READ hs (L2/L3-hot) in f32, quad butterfly ----
    float* ob = out + (((size_t)b) * LL + (l0 + pp)) * DD + cg * 8;
#pragma unroll
    for (int ks = 0; ks < 16; ++ks) {
      f32x4 v0 = *(const f32x4*)(ap + ks * 32);
      f32x4 v1 = *(const f32x4*)(ap + ks * 32 + 4);
      float x0 = av * v0.x, x1 = av * v0.y, x2 = av * v0.z, x3 = av * v0.w;
      float x4 = av * v1.x, x5 = av * v1.y, x6 = av * v1.z, x7 = av * v1.w;
      x0 = qadd<0xB1>(x0); x1 = qadd<0xB1>(x1);
      x2 = qadd<0xB1>(x2); x3 = qadd<0xB1>(x3);
      x4 = qadd<0xB1>(x4); x5 = qadd<0xB1>(x5);
      x6 = qadd<0xB1>(x6); x7 = qadd<0xB1>(x7);
      x0 = qadd<0x4E>(x0); x1 = qadd<0x4E>(x1);
      x2 = qadd<0x4E>(x2); x3 = qadd<0x4E>(x3);
      x4 = qadd<0x4E>(x4); x5 = qadd<0x4E>(x5);
      x6 = qadd<0x4E>(x6); x7 = qadd<0x4E>(x7);
      if (kk == 0) {
        f32x4 o0 = {x0, x1, x2, x3};
        f32x4 o1 = {x4, x5, x6, x7};
        __builtin_nontemporal_store(o0, (f32x4*)(ob + ks * 32));
        __builtin_nontemporal_store(o1, (f32x4*)(ob + ks * 32 + 4));
      }
    }
  }
}

extern "C" void kernel_launch(void* const* d_in, const int* in_sizes, int n_in,
                              void* d_out, int out_size, void* d_ws, size_t ws_size,
                              hipStream_t stream) {
  const float* hs   = (const float*)d_in[0];
  // d_in[1] = mask (int32) — unused: softmax over k is invariant to the
  // per-(b,l) uniform -1e4 shift, so the mask cannot affect x.
  const float* ln_w = (const float*)d_in[2];
  const float* ln_b = (const float*)d_in[3];
  const float* v_w  = (const float*)d_in[4];
  const float* vq   = (const float*)d_in[5];
  float* out = (float*)d_out;

  unsigned int* wf = (unsigned int*)d_ws;          // 128KB fragment-ordered bf16 W_h
  float* qb = (float*)((char*)d_ws + 131072);      // 512B q_bias

  prep_kernel<<<33, 256, 0, stream>>>(ln_w, ln_b, vq, wf, qb);
  agg_main<<<256, 512, 132096, stream>>>(hs, wf, qb, v_w, out);
}

// Round 17
// 159.207 us; speedup vs baseline: 4.9373x; 4.1058x over previous
//
#include <hip/hip_runtime.h>
#include <hip/hip_bf16.h>
#include <stdint.h>

// Problem constants
#define KK 4
#define BB 16
#define LL 4096
#define DD 512
#define HH 128

typedef __attribute__((ext_vector_type(8))) short bf16x8;
typedef __attribute__((ext_vector_type(4))) float f32x4;
typedef __attribute__((ext_vector_type(4))) unsigned int u32x4;

__device__ __forceinline__ unsigned int pack_bf16(float lo, float hi) {
  unsigned int a = __float_as_uint(lo);
  unsigned int b = __float_as_uint(hi);
  a = (a + 0x7FFFu + ((a >> 16) & 1u)) >> 16;   // RNE f32->bf16
  b = (b + 0x7FFFu + ((b >> 16) & 1u)) >> 16;
  return a | (b << 16);
}

// Raw barrier: LDS-ordering only (global loads stay in flight across it).
__device__ __forceinline__ void bar_lds() {
  __builtin_amdgcn_sched_barrier(0);
  asm volatile("s_waitcnt lgkmcnt(0)" ::: "memory");
  __builtin_amdgcn_s_barrier();
  __builtin_amdgcn_sched_barrier(0);
}

// x += row_shr:N (x) on the VALU pipe; rows of 16 lanes; 0-fill at row edge.
template <int N>
__device__ __forceinline__ float dpp_shr_add(float x) {
  int y = __builtin_amdgcn_update_dpp(0, __float_as_int(x), 0x110 | N, 0xF, 0xF,
                                      true);
  return x + __int_as_float(y);
}

// ---------------- kernel 0a: q_bias = W_q @ vq + ln_b ----------------
__global__ void qbias_kernel(const float* __restrict__ ln_w,
                             const float* __restrict__ ln_b,
                             const float* __restrict__ vq,
                             float* __restrict__ qb) {
  int h = threadIdx.x;
  if (h < HH) {
    float acc = ln_b[h];
    const float* wq = ln_w + (size_t)h * (DD + HH) + DD;
    for (int j = 0; j < HH; ++j) acc = fmaf(wq[j], vq[j], acc);
    qb[h] = acc;
  }
}

// ---------------- kernel 0b: W_h -> fragment-ordered bf16 (natural d) ----
// Chunk gid = (ks*8 + nt)*64 + lane holds 8 bf16 (MFMA B-fragment):
//   element j: W[nt*16 + (lane&15)][ks*32 + (lane>>4)*8 + j]
__global__ void wf_kernel(const float* __restrict__ ln_w,
                          unsigned int* __restrict__ wf) {
  int gid = blockIdx.x * 256 + threadIdx.x;   // 0..8191
  int ks = gid >> 9;
  int nt = (gid >> 6) & 7;
  int lane = gid & 63;
  int h = nt * 16 + (lane & 15);
  int d0 = ks * 32 + (lane >> 4) * 8;
  const float* src = ln_w + (size_t)h * (DD + HH) + d0;
  u32x4 v;
  v.x = pack_bf16(src[0], src[1]);
  v.y = pack_bf16(src[2], src[3]);
  v.z = pack_bf16(src[4], src[5]);
  v.w = pack_bf16(src[6], src[7]);
  *(u32x4*)(wf + (size_t)gid * 4) = v;
}

// ---------------- main fused kernel: ONE barrier per tile ----------------
// 256 blocks x 512 threads (1 block/CU, 8 waves), 32 tiles of 8 positions.
// TRIPLE-buffered bf16 A-tiles (3 x 32KB) let the per-tile barrier count
// drop from 2 (R4-R14, all ~150us) to 1: per tile t,
//   A(t): GEMM(P[t%3]) -> scores -> spv[t&1] -> write_stage(P[(t+1)%3])
//         -> issue_stage(t+2) -> BARRIER
//   B(t): softmax + weighted-sum reads P[t%3], then straight into A(t+1).
// Race audit (waves skew <= 1 barrier): GEMM(t+1) reads P[(t+1)%3], complete
// pre-barrier(t) by all waves; B(t) reads P[t%3] while A(t+1) writes
// P[(t+2)%3] (distinct); spv epoch-split by t&1; sv regs WAR-ordered within
// a wave. The 2-barrier variants' fixed per-tile cost (2x convergence +
// LDS drain + issue ramp) is the hypothesized ~25% of the 4.6us period.
// Cell map (R5/R8): wave wv -> nt = wv, M-subtiles st=0,1; W = 16 frags =
// 64 VGPR; sv = 32 VGPR; acc in AGPRs -> ~115 arch VGPR (no spill even at
// a 128 cap). A rows: row = pos*4 + k, XOR-swizzled by (row&7)<<4.
// C/D: pos = st*4 + (lane>>4), k = reg j.
__global__ __launch_bounds__(512) void agg_main(
    const float* __restrict__ hs, const unsigned int* __restrict__ wf,
    const float* __restrict__ qb, const float* __restrict__ vw,
    float* __restrict__ out) {
  extern __shared__ char smem[];
  char* bufA = smem;                             // 3 x 32768 B
  char* bufB = smem + 32768;
  char* bufC = smem + 65536;
  f32x4* spv = (f32x4*)(smem + 98304);           // [2 epoch][8 pos][8 wv]

  const int tid = threadIdx.x;
  const int lane = tid & 63;
  const int wv = tid >> 6;            // 0..7
  const int r = lane & 15;
  const int cg = lane >> 4;

  const int b = blockIdx.x >> 4;
  const int l0b = (blockIdx.x & 15) << 8;        // 256 l per block, 32 tiles of 8

  // ---- W fragments for nt = wv (h in [wv*16, wv*16+16)): 64 VGPR ----
  bf16x8 wreg[16];
#pragma unroll
  for (int ks = 0; ks < 16; ++ks)
    wreg[ks] = *(const bf16x8*)(wf + ((size_t)((ks * 8 + wv) * 64 + lane)) * 4);

  const float qbr = qb[wv * 16 + r];
  const float vwr = vw[wv * 16 + r];

  // ---- staging helpers (chunk i: row = i*8+wv; d pre-swizzled) ----
  f32x4 sv[8];
  auto issue_stage = [&](int l0) {
#pragma unroll
    for (int i = 0; i < 4; ++i) {
      int row = i * 8 + wv;
      int k = row & 3, pos = row >> 2;
      int d0 = (lane ^ (row & 7)) * 8;
      const float* p = hs + (((size_t)(k * BB + b)) * LL + l0 + pos) * DD + d0;
      sv[i * 2]     = *(const f32x4*)(p);
      sv[i * 2 + 1] = *(const f32x4*)(p + 4);
    }
  };
  auto write_stage = [&](char* dst) {
#pragma unroll
    for (int i = 0; i < 4; ++i) {
      u32x4 pk;
      pk.x = pack_bf16(sv[i * 2].x, sv[i * 2].y);
      pk.y = pack_bf16(sv[i * 2].z, sv[i * 2].w);
      pk.z = pack_bf16(sv[i * 2 + 1].x, sv[i * 2 + 1].y);
      pk.w = pack_bf16(sv[i * 2 + 1].z, sv[i * 2 + 1].w);
      *(u32x4*)(dst + i * 8192 + tid * 16) = pk;   // physical = logical ^ ((row&7)<<4)
    }
  };

  // ---- prologue: tile 0 staged into bufA; tile 1 loads in flight (sv) ----
  issue_stage(l0b);
  write_stage(bufA);
  issue_stage(l0b + 8);
  bar_lds();

  char* p0 = bufA;   // P[t%3]   : current tile
  char* p1 = bufB;   // P[(t+1)%3]: write target (tile t+1)
  char* p2 = bufC;   // P[(t+2)%3]: in-flight spare

  for (int t = 0; t < 32; ++t) {
    const int l0 = l0b + t * 8;
    f32x4* spvE = spv + (t & 1) * 64;

    // ======== phase A ========
    // ---- GEMM: 2 A-reads + 2 MFMA per K-step (nt = wv, st = 0,1) ----
    f32x4 acc0 = {0.f, 0.f, 0.f, 0.f};
    f32x4 acc1 = {0.f, 0.f, 0.f, 0.f};
    const int swz = (r & 7) << 4;
#pragma unroll
    for (int ks = 0; ks < 16; ++ks) {
      int inner = (ks * 64 + cg * 16) ^ swz;
      bf16x8 a0 = *(const bf16x8*)(p0 + r * 1024 + inner);
      bf16x8 a1 = *(const bf16x8*)(p0 + (16 + r) * 1024 + inner);
      acc0 = __builtin_amdgcn_mfma_f32_16x16x32_bf16(a0, wreg[ks], acc0, 0, 0, 0);
      acc1 = __builtin_amdgcn_mfma_f32_16x16x32_bf16(a1, wreg[ks], acc1, 0, 0, 0);
    }

    // ---- scores: ps = vw[h]*tanh(z+qb[h]) summed over this wave's 16 h ----
    float ps[8];
#pragma unroll
    for (int st = 0; st < 2; ++st) {
      f32x4 acc = st ? acc1 : acc0;
#pragma unroll
      for (int j = 0; j < 4; ++j) {
        float z = acc[j] + qbr;
        z = fminf(15.f, fmaxf(-15.f, z));
        float e = __expf(-2.f * z);
        float th = (1.f - e) * __builtin_amdgcn_rcpf(1.f + e);
        ps[st * 4 + j] = vwr * th;
      }
    }
#pragma unroll
    for (int q = 0; q < 8; ++q) {
      ps[q] = dpp_shr_add<1>(ps[q]);
      ps[q] = dpp_shr_add<2>(ps[q]);
      ps[q] = dpp_shr_add<4>(ps[q]);
      ps[q] = dpp_shr_add<8>(ps[q]);
    }
    if (r == 15) {
      f32x4 v0 = {ps[0], ps[1], ps[2], ps[3]};
      f32x4 v1 = {ps[4], ps[5], ps[6], ps[7]};
      spvE[(0 + cg) * 8 + wv] = v0;   // pos = cg
      spvE[(4 + cg) * 8 + wv] = v1;   // pos = 4 + cg
    }

    // ---- publish tile t+1 into p1 (sv from issue at A(t-1)); then issue
    // tile t+2 loads into sv (WAR ordered within the wave) ----
    if (t < 31) write_stage(p1);
    if (t < 30) issue_stage(l0 + 16);

    bar_lds();                        // the ONLY barrier of the tile

    // ======== phase B ========
    // ---- softmax over k for pos = wv (8 broadcast reads) ----
    // mask dropped: uniform per-(b,l) shift is softmax-invariant
    float a0, a1, a2, a3;
    {
      f32x4 s = spvE[wv * 8 + 0];
#pragma unroll
      for (int w2 = 1; w2 < 8; ++w2) s += spvE[wv * 8 + w2];
      float mx = fmaxf(fmaxf(s.x, s.y), fmaxf(s.z, s.w));
      float e0 = __expf(s.x - mx), e1 = __expf(s.y - mx);
      float e2 = __expf(s.z - mx), e3 = __expf(s.w - mx);
      float inv = __builtin_amdgcn_rcpf(e0 + e1 + e2 + e3);
      a0 = e0 * inv; a1 = e1 * inv; a2 = e2 * inv; a3 = e3 * inv;
    }

    // ---- weighted sum: wave wv owns pos = wv (reads p0 inline) ----
    {
      float x[8];
#pragma unroll
      for (int j = 0; j < 8; ++j) x[j] = 0.f;
#pragma unroll
      for (int k = 0; k < 4; ++k) {
        int row = wv * 4 + k;
        float ak = k == 0 ? a0 : (k == 1 ? a1 : (k == 2 ? a2 : a3));
        u32x4 u = *(const u32x4*)(p0 + row * 1024 +
                                  ((lane * 16) ^ ((row & 7) << 4)));
        x[0] = fmaf(ak, __uint_as_float(u.x << 16), x[0]);
        x[1] = fmaf(ak, __uint_as_float(u.x & 0xffff0000u), x[1]);
        x[2] = fmaf(ak, __uint_as_float(u.y << 16), x[2]);
        x[3] = fmaf(ak, __uint_as_float(u.y & 0xffff0000u), x[3]);
        x[4] = fmaf(ak, __uint_as_float(u.z << 16), x[4]);
        x[5] = fmaf(ak, __uint_as_float(u.z & 0xffff0000u), x[5]);
        x[6] = fmaf(ak, __uint_as_float(u.w << 16), x[6]);
        x[7] = fmaf(ak, __uint_as_float(u.w & 0xffff0000u), x[7]);
      }
      float* ob = out + (((size_t)b) * LL + l0 + wv) * DD + lane * 8;
      f32x4 o0 = {x[0], x[1], x[2], x[3]};
      f32x4 o1 = {x[4], x[5], x[6], x[7]};
      __builtin_nontemporal_store(o0, (f32x4*)ob);
      __builtin_nontemporal_store(o1, (f32x4*)(ob + 4));
    }

    // rotate triple buffer: (p0,p1,p2) <- (p1,p2,p0)
    char* tmp = p0;
    p0 = p1;
    p1 = p2;
    p2 = tmp;
  }
}

extern "C" void kernel_launch(void* const* d_in, const int* in_sizes, int n_in,
                              void* d_out, int out_size, void* d_ws, size_t ws_size,
                              hipStream_t stream) {
  const float* hs   = (const float*)d_in[0];
  // d_in[1] = mask (int32) — unused: softmax over k is invariant to the
  // per-(b,l) uniform -1e4 shift, so the mask cannot affect x.
  const float* ln_w = (const float*)d_in[2];
  const float* ln_b = (const float*)d_in[3];
  const float* v_w  = (const float*)d_in[4];
  const float* vq   = (const float*)d_in[5];
  float* out = (float*)d_out;

  unsigned int* wf = (unsigned int*)d_ws;          // 128KB fragment-ordered bf16 W_h
  float* qb = (float*)((char*)d_ws + 131072);      // 512B q_bias

  qbias_kernel<<<1, 128, 0, stream>>>(ln_w, ln_b, vq, qb);
  wf_kernel<<<32, 256, 0, stream>>>(ln_w, wf);
  agg_main<<<256, 512, 100352, stream>>>(hs, wf, qb, v_w, out);
}